// Round 11
// baseline (1974.243 us; speedup 1.0000x reference)
//
#include <hip/hip_runtime.h>
#include <hip/hip_bf16.h>
#include <stdint.h>

// LSTM: T=512, B=64, D=1024, H=1024, gates order i,f,g,o
#define T_STEPS 512
#define BATCH   64
#define DIM     1024
#define HID     1024
#define NG      4096                 // 4*HID
#define MROWS   (T_STEPS * BATCH)    // 32768

typedef __bf16 bf16;
typedef __bf16 bf16x4 __attribute__((ext_vector_type(4)));
typedef __bf16 bf16x8 __attribute__((ext_vector_type(8)));
typedef float  f32x4  __attribute__((ext_vector_type(4)));
typedef unsigned int u32;
typedef u32 u32x2 __attribute__((ext_vector_type(2)));
typedef u32 u32x4 __attribute__((ext_vector_type(4)));

__device__ __forceinline__ void g2lds16(const void* g, void* l) {
    __builtin_amdgcn_global_load_lds(
        (const __attribute__((address_space(1))) void*)g,
        (__attribute__((address_space(3))) void*)l, 16, 0, 0);
}

__device__ __forceinline__ float fsigmoid(float x) {
    return 1.0f / (1.0f + __expf(-x));   // safe at +-inf
}
__device__ __forceinline__ float ftanh_(float x) {
    return 1.0f - 2.0f / (__expf(2.0f * x) + 1.0f);   // safe at +-inf
}

// ---- LLC-coherent (bypass L1+L2) ops: proven in R2/R3/R8/R10 ----
__device__ __forceinline__ u32x4 load16_cc(const void* p) {
    u32x4 r;
    asm volatile("global_load_dwordx4 %0, %1, off sc0 sc1" : "=v"(r) : "v"(p) : "memory");
    return r;
}
__device__ __forceinline__ void store2_cc(void* p, u32 v) {
    asm volatile("global_store_short %0, %1, off sc0 sc1" :: "v"(p), "v"(v) : "memory");
}
__device__ __forceinline__ u32x2 load8_cached(const void* p) {
    u32x2 r;
    asm volatile("global_load_dwordx2 %0, %1, off" : "=v"(r) : "v"(p) : "memory");
    return r;
}
__device__ __forceinline__ void store4_f32(float* p, float v) {
    asm volatile("global_store_dword %0, %1, off" :: "v"(p), "v"(v) : "memory");
}
#define WAITVM(n) asm volatile("s_waitcnt vmcnt(" #n ")" ::: "memory")

// ---------------------------------------------------------------------------
// prep: fp32->bf16 conversions, W_ih column-permute (n' = (n&1023)*4 + (n>>10)),
// W_hh scatter into MFMA-fragment order (wfrag), bias sum (permuted),
// zero h0 buffer and barrier flags (re-zeroed every launch => replay-safe).
// ---------------------------------------------------------------------------
__global__ __launch_bounds__(256) void prep_kernel(
    const float* __restrict__ x,   const float* __restrict__ wih,
    const float* __restrict__ whh, const float* __restrict__ bih,
    const float* __restrict__ bhh,
    bf16* __restrict__ xb, bf16* __restrict__ wihp, bf16* __restrict__ wfrag,
    float* __restrict__ bsump, bf16* __restrict__ hbuf, u32* __restrict__ flags)
{
    const int nt  = gridDim.x * blockDim.x;
    const int gid = blockIdx.x * blockDim.x + threadIdx.x;

    for (int i = gid; i < MROWS * DIM / 4; i += nt) {
        f32x4 v = *(const f32x4*)(x + (size_t)i * 4);
        bf16x4 o = {(bf16)v[0], (bf16)v[1], (bf16)v[2], (bf16)v[3]};
        *(bf16x4*)(xb + (size_t)i * 4) = o;
    }
    for (int i = gid; i < NG * (DIM / 4); i += nt) {
        const int n = i >> 8, c4 = (i & 255) * 4;
        f32x4 v = *(const f32x4*)(wih + (size_t)n * DIM + c4);
        bf16x4 o = {(bf16)v[0], (bf16)v[1], (bf16)v[2], (bf16)v[3]};
        const int np = ((n & 1023) << 2) | (n >> 10);
        *(bf16x4*)(wihp + (size_t)np * DIM + c4) = o;
    }
    // wfrag: element i = ((hg*4 + wv)*64 + f)*64 + lane, f = kk*8+n;
    // grow = (lane&3)*1024 + hg*32 + n*4 + ((lane&15)>>2), k0 = wv*256+kk*32+(lane>>4)*8
    for (int i = gid; i < NG * HID / 8; i += nt) {
        const int lane = i & 63;
        const int f    = (i >> 6) & 63;
        const int wv   = (i >> 12) & 3;
        const int hg   = i >> 14;
        const int n = f & 7, kk = f >> 3;
        const int grow = (lane & 3) * 1024 + hg * 32 + n * 4 + ((lane & 15) >> 2);
        const int k0   = wv * 256 + kk * 32 + (lane >> 4) * 8;
        f32x4 v0 = *(const f32x4*)(whh + (size_t)grow * HID + k0);
        f32x4 v1 = *(const f32x4*)(whh + (size_t)grow * HID + k0 + 4);
        bf16x8 o = {(bf16)v0[0], (bf16)v0[1], (bf16)v0[2], (bf16)v0[3],
                    (bf16)v1[0], (bf16)v1[1], (bf16)v1[2], (bf16)v1[3]};
        *(bf16x8*)(wfrag + (size_t)i * 8) = o;
    }
    for (int i = gid; i < NG; i += nt)
        bsump[((i & 1023) << 2) | (i >> 10)] = bih[i] + bhh[i];
    for (int i = gid; i < BATCH * HID / 4; i += nt) {
        bf16x4 z = {(bf16)0.f, (bf16)0.f, (bf16)0.f, (bf16)0.f};
        *(bf16x4*)(hbuf + (size_t)i * 4) = z;   // h[buf 0] = 0
    }
    for (int i = gid; i < 256 * 16; i += nt)
        flags[i] = 0u;
}

// ---------------------------------------------------------------------------
// xg GEMM: C[32768,4096] = xb[32768,1024] @ wihp^T + bsump, bf16 out.
// Bijective XCD swizzle (nwg=8192 % 8 == 0): XCD x owns by-panels
// [x*32, x*32+32) exclusively -> A-panel stays hot in that XCD's L2.
// ---------------------------------------------------------------------------
__global__ __launch_bounds__(256) void gemm_kernel(
    const bf16* __restrict__ A, const bf16* __restrict__ B,
    const float* __restrict__ bsum, bf16* __restrict__ xgp)
{
    __shared__ char lds[16384];
    char* As = lds;
    char* Bs = lds + 8192;

    const int tid  = threadIdx.x;
    const int lane = tid & 63;
    const int wv   = tid >> 6;
    const int wr   = wv >> 1, wc = wv & 1;
    const int wgid = (blockIdx.x & 7) * 1024 + (blockIdx.x >> 3);  // XCD swizzle
    const int bx   = wgid & 31;   // N tile
    const int by   = wgid >> 5;   // M tile
    const int m0   = by * 128, n0 = bx * 128;

    f32x4 acc[4][4] = {};

    const int r4 = tid >> 2;
    const int c8 = (tid & 3) * 8;
    const size_t arow0 = (size_t)(m0 +      r4) * DIM + c8;
    const size_t arow1 = (size_t)(m0 + 64 + r4) * DIM + c8;
    const size_t brow0 = (size_t)(n0 +      r4) * DIM + c8;
    const size_t brow1 = (size_t)(n0 + 64 + r4) * DIM + c8;
    const int ldsoff = tid * 16;

    for (int k0 = 0; k0 < DIM; k0 += 32) {
        g2lds16(A + arow0 + k0, As + ldsoff);
        g2lds16(A + arow1 + k0, As + 4096 + ldsoff);
        g2lds16(B + brow0 + k0, Bs + ldsoff);
        g2lds16(B + brow1 + k0, Bs + 4096 + ldsoff);
        __syncthreads();

        bf16x8 af[4], bfr[4];
        #pragma unroll
        for (int i = 0; i < 4; ++i) {
            af[i]  = *(const bf16x8*)(As + (wr*64 + i*16 + (lane & 15))*64 + (lane >> 4)*16);
            bfr[i] = *(const bf16x8*)(Bs + (wc*64 + i*16 + (lane & 15))*64 + (lane >> 4)*16);
        }
        #pragma unroll
        for (int i = 0; i < 4; ++i)
            #pragma unroll
            for (int j = 0; j < 4; ++j)
                acc[i][j] = __builtin_amdgcn_mfma_f32_16x16x32_bf16(
                    af[i], bfr[j], acc[i][j], 0, 0, 0);
        __syncthreads();
    }

    #pragma unroll
    for (int j = 0; j < 4; ++j) {
        const int nn = n0 + wc*64 + j*16 + (lane & 15);
        const float bias = bsum[nn];
        #pragma unroll
        for (int i = 0; i < 4; ++i) {
            #pragma unroll
            for (int r = 0; r < 4; ++r) {
                const int mm = m0 + wr*64 + i*16 + ((lane >> 4) << 2) + r;
                xgp[(size_t)mm * NG + nn] = (bf16)(acc[i][j][r] + bias);
            }
        }
    }
}

// ---------------------------------------------------------------------------
// Persistent recurrent kernel — R10's proven structure with two refinements:
// 1) hstage row pitch 2064 B (pad, no XOR): conflict-free ds_write/ds_read
//    per 8-lane groups (row stride 516 words -> bank offset 4/row). Allowed
//    because staging is reg-staged (pad forbidden only for global_load_lds).
// 2) Split poll+load: wave wv's K-half1 (k-local [0,128)) comes from
//    producers wv*8+0..3, half2 from wv*8+4..7. Sequence:
//      poll(0..3) -> issue chunks c0,c1 -> poll(4..7) [its vmcnt(0) drains
//      c0,c1 during the poll] -> issue c2,c3 + out(t-1) + xg(next) ->
//      LDS-write half1 + MFMA half1 (hides c2,c3) -> WAITVM(2) ->
//      LDS-write half2 + MFMA half2.
//    Chunk c covers k-quarter c*64..+64 x all 8 rows; per-8-lane groups are
//    128 B contiguous in both global and LDS.
// Flags, W fragments, gbuf reduce, elementwise, E-tail: R10 verbatim
// (every flag-protocol invariant unchanged; full-poll-before-MFMA holds
// since poll2 precedes all MFMA, so D-sync still certifies the WG).
// ---------------------------------------------------------------------------
__global__ __launch_bounds__(256, 1) void lstm_kernel(
    const bf16* __restrict__ xgp, const bf16* __restrict__ wfrag,
    bf16* __restrict__ hbuf, u32* __restrict__ flags, float* __restrict__ out)
{
    __shared__ char  hstage[8 * 2064];  // h[8 rows][1024 k] bf16, pitch 2064
    __shared__ float gbuf[4][8][136];   // [wave][batch row][gate col]

    const int tid  = threadIdx.x;
    const int lane = tid & 63;
    const int wv   = tid >> 6;
    const int wg   = blockIdx.x;
    const int hg   = wg & 31;
    const int bg   = wg >> 5;

    // W fragments -> 256 regs/lane (64 x bf16x8), coalesced 16B loads
    bf16x8 wreg[64];
    {
        const bf16* wb = wfrag + ((size_t)(hg * 4 + wv) * 4096 + lane) * 8;
        #pragma unroll
        for (int f = 0; f < 64; ++f)
            wreg[f] = *(const bf16x8*)(wb + (size_t)f * 512);
    }

    const int frow  = lane & 15;
    const int b_el  = tid >> 5;                       // 0..7
    const int j_el  = tid & 31;                       // 0..31
    const int hid   = hg * 32 + j_el;

    // staging: chunk c = k-quarter c*64..+64 x rows 0..7.
    // lane -> row r = lane>>3, k8 = lane&7. 8-lane groups: 128B contiguous.
    const int goff = (lane >> 3) * 2048 + wv * 512 + (lane & 7) * 16;  // global
    const int woff = (lane >> 3) * 2064 + wv * 512 + (lane & 7) * 16;  // LDS
    // read: frag (kk,q): byte = rbase*2064 + wv*512 + q*16 + kk*64
    const int rbase = frow & 7;
    const int cbase = rbase * 2064 + wv * 512 + (lane >> 4) * 16;

    const u32* pollpA = flags + ((bg * 32 + wv * 8 + (lane & 3)) << 4);
    const u32* pollpB = flags + ((bg * 32 + wv * 8 + 4 + (lane & 3)) << 4);
    u32* myflag       = flags + ((bg * 32 + hg) << 4);

    float c = 0.f;
    float hv_prev = 0.f;
    u32x2 xr = load8_cached(xgp + (size_t)(bg * 8 + b_el) * NG + hid * 4);

    #pragma unroll 1
    for (int step = 0; step < T_STEPS; ++step) {
        // A1: poll this wave's first 4 producers (K-half1 ready)
        while (__hip_atomic_load(pollpA, __ATOMIC_RELAXED,
                                 __HIP_MEMORY_SCOPE_AGENT) < (u32)step)
            __builtin_amdgcn_s_sleep(1);

        // B1: issue chunks 0,1 (half1)
        const char* hbp = (const char*)(hbuf + (step & 1) * (BATCH * HID)
                                             + (size_t)(bg * 8) * HID);
        u32x4 s0 = load16_cc(hbp + goff);
        u32x4 s1 = load16_cc(hbp + goff + 128);

        // A2: poll last 4 producers; its vmcnt(0) drains s0,s1 during the wait
        while (__hip_atomic_load(pollpB, __ATOMIC_RELAXED,
                                 __HIP_MEMORY_SCOPE_AGENT) < (u32)step)
            __builtin_amdgcn_s_sleep(1);

        // B2: issue chunks 2,3 + out(t-1) + xg(next): exactly 4 VMEM in flight
        u32x4 s2 = load16_cc(hbp + goff + 256);
        u32x4 s3 = load16_cc(hbp + goff + 384);
        const int orow = (step == 0) ? 0 : step - 1;
        store4_f32(out + (size_t)(orow * BATCH + bg * 8 + b_el) * HID + hid, hv_prev);
        const int nx = (step + 1 < T_STEPS) ? step + 1 : step;
        u32x2 xr_n = load8_cached(xgp + ((size_t)(nx * BATCH) + bg * 8 + b_el) * NG
                                      + hid * 4);

        // C1: stage + compute half1 (s0,s1 already drained by poll A2)
        *(u32x4*)(hstage + woff)       = s0;
        *(u32x4*)(hstage + woff + 128) = s1;
        f32x4 acc[8] = {};
        #pragma unroll
        for (int kk = 0; kk < 4; ++kk) {
            bf16x8 a = *(const bf16x8*)(hstage + cbase + kk * 64);
            #pragma unroll
            for (int n = 0; n < 8; ++n)
                acc[n] = __builtin_amdgcn_mfma_f32_16x16x32_bf16(
                    a, wreg[kk * 8 + n], acc[n], 0, 0, 0);
        }

        // C2: chunks 2,3 landed under MFMA half1
        WAITVM(2);
        __builtin_amdgcn_sched_barrier(0);
        *(u32x4*)(hstage + woff + 256) = s2;
        *(u32x4*)(hstage + woff + 384) = s3;
        #pragma unroll
        for (int kk = 4; kk < 8; ++kk) {
            bf16x8 a = *(const bf16x8*)(hstage + cbase + kk * 64);
            #pragma unroll
            for (int n = 0; n < 8; ++n)
                acc[n] = __builtin_amdgcn_mfma_f32_16x16x32_bf16(
                    a, wreg[kk * 8 + n], acc[n], 0, 0, 0);
        }

        // D: cross-wave reduce staging (valid batch rows live in lanes 0..31)
        if (lane < 32) {
            const int q = lane >> 4;
            #pragma unroll
            for (int n = 0; n < 8; ++n)
                #pragma unroll
                for (int r = 0; r < 4; ++r)
                    gbuf[wv][q * 4 + r][n * 16 + frow] = acc[n][r];
        }
        __syncthreads();

        // E: elementwise (one thread per (batch row, hid unit))
        bf16x4 xv = __builtin_bit_cast(bf16x4, xr);
        float P[4];
        #pragma unroll
        for (int g = 0; g < 4; ++g)
            P[g] = gbuf[0][b_el][j_el * 4 + g] + gbuf[1][b_el][j_el * 4 + g]
                 + gbuf[2][b_el][j_el * 4 + g] + gbuf[3][b_el][j_el * 4 + g]
                 + (float)xv[g];
        const float ig = fsigmoid(P[0]);
        const float fg = fsigmoid(P[1]);
        const float gg = ftanh_(P[2]);
        const float og = fsigmoid(P[3]);
        c = fg * c + ig * gg;
        const float hv = og * ftanh_(c);

        const bf16 h16 = (bf16)hv;
        store2_cc(hbuf + ((step & 1) ^ 1) * (BATCH * HID)
                       + (size_t)(bg * 8 + b_el) * HID + hid,
                  (u32)__builtin_bit_cast(unsigned short, h16));
        WAITVM(0);                        // h-store acked at LLC (others already done)
        __builtin_amdgcn_sched_barrier(0);
        __syncthreads();                  // all waves of this WG acked
        if (tid == 0)
            __hip_atomic_store(myflag, (u32)(step + 1),
                               __ATOMIC_RELAXED, __HIP_MEMORY_SCOPE_AGENT);
        hv_prev = hv;
        xr = xr_n;
    }

    // epilogue: final out row
    store4_f32(out + (size_t)((T_STEPS - 1) * BATCH + bg * 8 + b_el) * HID + hid,
               hv_prev);
}

// ---------------------------------------------------------------------------
extern "C" void kernel_launch(void* const* d_in, const int* in_sizes, int n_in,
                              void* d_out, int out_size, void* d_ws, size_t ws_size,
                              hipStream_t stream) {
    const float* x   = (const float*)d_in[0];   // [512,64,1024]
    const float* wih = (const float*)d_in[1];   // [4096,1024]
    const float* whh = (const float*)d_in[2];   // [4096,1024]
    const float* bih = (const float*)d_in[3];   // [4096]
    const float* bhh = (const float*)d_in[4];   // [4096]
    float* out = (float*)d_out;                 // [512,64,1024]

    char* ws = (char*)d_ws;
    size_t off = 0;
    bf16* xgp   = (bf16*)(ws + off); off += (size_t)MROWS * NG * 2;      // 256 MB
    bf16* xb    = (bf16*)(ws + off); off += (size_t)MROWS * DIM * 2;     //  64 MB
    bf16* wihp  = (bf16*)(ws + off); off += (size_t)NG * DIM * 2;        //   8 MB
    bf16* wfrag = (bf16*)(ws + off); off += (size_t)NG * HID * 2;        //   8 MB
    float* bsum = (float*)(ws + off); off += (size_t)NG * 4;             //  16 KB
    bf16* hbuf  = (bf16*)(ws + off); off += (size_t)2 * BATCH * HID * 2; // 256 KB
    u32* flags  = (u32*)(ws + off); off += 256 * 16 * 4;                 //  16 KB
    (void)ws_size; (void)in_sizes; (void)n_in; (void)out_size;

    prep_kernel<<<2048, 256, 0, stream>>>(x, wih, whh, bih, bhh,
                                          xb, wihp, wfrag, bsum, hbuf, flags);
    gemm_kernel<<<8192, 256, 0, stream>>>(xb, wihp, bsum, xgp);
    lstm_kernel<<<256, 256, 0, stream>>>(xgp, wfrag, hbuf, flags, out);
}

// Round 12
// 1894.695 us; speedup vs baseline: 1.0420x; 1.0420x over previous
//
#include <hip/hip_runtime.h>
#include <hip/hip_bf16.h>
#include <stdint.h>

// LSTM: T=512, B=64, D=1024, H=1024, gates order i,f,g,o
#define T_STEPS 512
#define BATCH   64
#define DIM     1024
#define HID     1024
#define NG      4096                 // 4*HID
#define MROWS   (T_STEPS * BATCH)    // 32768

typedef __bf16 bf16;
typedef __bf16 bf16x4 __attribute__((ext_vector_type(4)));
typedef __bf16 bf16x8 __attribute__((ext_vector_type(8)));
typedef float  f32x4  __attribute__((ext_vector_type(4)));
typedef unsigned int u32;
typedef u32 u32x2 __attribute__((ext_vector_type(2)));
typedef u32 u32x4 __attribute__((ext_vector_type(4)));

__device__ __forceinline__ void g2lds16(const void* g, void* l) {
    __builtin_amdgcn_global_load_lds(
        (const __attribute__((address_space(1))) void*)g,
        (__attribute__((address_space(3))) void*)l, 16, 0, 0);
}

__device__ __forceinline__ float fsigmoid(float x) {
    return 1.0f / (1.0f + __expf(-x));   // safe at +-inf
}
__device__ __forceinline__ float ftanh_(float x) {
    return 1.0f - 2.0f / (__expf(2.0f * x) + 1.0f);   // safe at +-inf
}

// ---- LLC-coherent (bypass L1+L2) ops: proven in R2/R3/R8/R10/R11 ----
__device__ __forceinline__ u32x4 load16_cc(const void* p) {
    u32x4 r;
    asm volatile("global_load_dwordx4 %0, %1, off sc0 sc1" : "=v"(r) : "v"(p) : "memory");
    return r;
}
__device__ __forceinline__ void store2_cc(void* p, u32 v) {
    asm volatile("global_store_short %0, %1, off sc0 sc1" :: "v"(p), "v"(v) : "memory");
}
__device__ __forceinline__ u32x2 load8_cached(const void* p) {
    u32x2 r;
    asm volatile("global_load_dwordx2 %0, %1, off" : "=v"(r) : "v"(p) : "memory");
    return r;
}
__device__ __forceinline__ void store4_f32(float* p, float v) {
    asm volatile("global_store_dword %0, %1, off" :: "v"(p), "v"(v) : "memory");
}
#define WAITVM(n) asm volatile("s_waitcnt vmcnt(" #n ")" ::: "memory")

// ---------------------------------------------------------------------------
// prep: fp32->bf16 conversions, W_ih column-permute (n' = (n&1023)*4 + (n>>10)),
// W_hh scatter into MFMA-fragment order (wfrag), bias sum (permuted),
// zero h0 buffer and barrier flags (re-zeroed every launch => replay-safe).
// ---------------------------------------------------------------------------
__global__ __launch_bounds__(256) void prep_kernel(
    const float* __restrict__ x,   const float* __restrict__ wih,
    const float* __restrict__ whh, const float* __restrict__ bih,
    const float* __restrict__ bhh,
    bf16* __restrict__ xb, bf16* __restrict__ wihp, bf16* __restrict__ wfrag,
    float* __restrict__ bsump, bf16* __restrict__ hbuf, u32* __restrict__ flags)
{
    const int nt  = gridDim.x * blockDim.x;
    const int gid = blockIdx.x * blockDim.x + threadIdx.x;

    for (int i = gid; i < MROWS * DIM / 4; i += nt) {
        f32x4 v = *(const f32x4*)(x + (size_t)i * 4);
        bf16x4 o = {(bf16)v[0], (bf16)v[1], (bf16)v[2], (bf16)v[3]};
        *(bf16x4*)(xb + (size_t)i * 4) = o;
    }
    for (int i = gid; i < NG * (DIM / 4); i += nt) {
        const int n = i >> 8, c4 = (i & 255) * 4;
        f32x4 v = *(const f32x4*)(wih + (size_t)n * DIM + c4);
        bf16x4 o = {(bf16)v[0], (bf16)v[1], (bf16)v[2], (bf16)v[3]};
        const int np = ((n & 1023) << 2) | (n >> 10);
        *(bf16x4*)(wihp + (size_t)np * DIM + c4) = o;
    }
    // wfrag: element i = ((hg*4 + wv)*64 + f)*64 + lane, f = kk*8+n;
    // grow = (lane&3)*1024 + hg*32 + n*4 + ((lane&15)>>2), k0 = wv*256+kk*32+(lane>>4)*8
    for (int i = gid; i < NG * HID / 8; i += nt) {
        const int lane = i & 63;
        const int f    = (i >> 6) & 63;
        const int wv   = (i >> 12) & 3;
        const int hg   = i >> 14;
        const int n = f & 7, kk = f >> 3;
        const int grow = (lane & 3) * 1024 + hg * 32 + n * 4 + ((lane & 15) >> 2);
        const int k0   = wv * 256 + kk * 32 + (lane >> 4) * 8;
        f32x4 v0 = *(const f32x4*)(whh + (size_t)grow * HID + k0);
        f32x4 v1 = *(const f32x4*)(whh + (size_t)grow * HID + k0 + 4);
        bf16x8 o = {(bf16)v0[0], (bf16)v0[1], (bf16)v0[2], (bf16)v0[3],
                    (bf16)v1[0], (bf16)v1[1], (bf16)v1[2], (bf16)v1[3]};
        *(bf16x8*)(wfrag + (size_t)i * 8) = o;
    }
    for (int i = gid; i < NG; i += nt)
        bsump[((i & 1023) << 2) | (i >> 10)] = bih[i] + bhh[i];
    for (int i = gid; i < BATCH * HID / 4; i += nt) {
        bf16x4 z = {(bf16)0.f, (bf16)0.f, (bf16)0.f, (bf16)0.f};
        *(bf16x4*)(hbuf + (size_t)i * 4) = z;   // h[buf 0] = 0
    }
    for (int i = gid; i < 256 * 16; i += nt)
        flags[i] = 0u;
}

// ---------------------------------------------------------------------------
// xg GEMM: C[32768,4096] = xb[32768,1024] @ wihp^T + bsump, bf16 out.
// Default block mapping (R10): round-robin XCD dispatch gives each XCD a
// 4-N-panel working set (~1 MB, L2-resident) — measured better than the
// contiguous-M-chunk swizzle (R11: +85 us regression, reverted).
// ---------------------------------------------------------------------------
__global__ __launch_bounds__(256) void gemm_kernel(
    const bf16* __restrict__ A, const bf16* __restrict__ B,
    const float* __restrict__ bsum, bf16* __restrict__ xgp)
{
    __shared__ char lds[16384];
    char* As = lds;
    char* Bs = lds + 8192;

    const int tid  = threadIdx.x;
    const int lane = tid & 63;
    const int wv   = tid >> 6;
    const int wr   = wv >> 1, wc = wv & 1;
    const int bx   = blockIdx.x & 31;   // N tile
    const int by   = blockIdx.x >> 5;   // M tile
    const int m0   = by * 128, n0 = bx * 128;

    f32x4 acc[4][4] = {};

    const int r4 = tid >> 2;
    const int c8 = (tid & 3) * 8;
    const size_t arow0 = (size_t)(m0 +      r4) * DIM + c8;
    const size_t arow1 = (size_t)(m0 + 64 + r4) * DIM + c8;
    const size_t brow0 = (size_t)(n0 +      r4) * DIM + c8;
    const size_t brow1 = (size_t)(n0 + 64 + r4) * DIM + c8;
    const int ldsoff = tid * 16;

    for (int k0 = 0; k0 < DIM; k0 += 32) {
        g2lds16(A + arow0 + k0, As + ldsoff);
        g2lds16(A + arow1 + k0, As + 4096 + ldsoff);
        g2lds16(B + brow0 + k0, Bs + ldsoff);
        g2lds16(B + brow1 + k0, Bs + 4096 + ldsoff);
        __syncthreads();

        bf16x8 af[4], bfr[4];
        #pragma unroll
        for (int i = 0; i < 4; ++i) {
            af[i]  = *(const bf16x8*)(As + (wr*64 + i*16 + (lane & 15))*64 + (lane >> 4)*16);
            bfr[i] = *(const bf16x8*)(Bs + (wc*64 + i*16 + (lane & 15))*64 + (lane >> 4)*16);
        }
        #pragma unroll
        for (int i = 0; i < 4; ++i)
            #pragma unroll
            for (int j = 0; j < 4; ++j)
                acc[i][j] = __builtin_amdgcn_mfma_f32_16x16x32_bf16(
                    af[i], bfr[j], acc[i][j], 0, 0, 0);
        __syncthreads();
    }

    #pragma unroll
    for (int j = 0; j < 4; ++j) {
        const int nn = n0 + wc*64 + j*16 + (lane & 15);
        const float bias = bsum[nn];
        #pragma unroll
        for (int i = 0; i < 4; ++i) {
            #pragma unroll
            for (int r = 0; r < 4; ++r) {
                const int mm = m0 + wr*64 + i*16 + ((lane >> 4) << 2) + r;
                xgp[(size_t)mm * NG + nn] = (bf16)(acc[i][j][r] + bias);
            }
        }
    }
}

// ---------------------------------------------------------------------------
// Persistent recurrent kernel — R11 structure with one E-tail reorder:
// the out-store (HBM) and xg-prefetch are issued AFTER the h-store, so
// WAITVM(2) acks ONLY the h-store before the flag (removes the HBM store
// ack from the flag-publish path). Their acks drain inside the next poll's
// implicit vmcnt(0) (idle spin time). C2's wait becomes WAITVM(0) (only
// s2,s3 outstanding there). Split-poll staging pipeline from R11 kept:
//   A1 poll(prod 0..3) -> B1 issue s0,s1 -> A2 poll(4..7) [drains s0,s1]
//   -> B2 issue s2,s3 -> C1 stage+MFMA half1 -> WAITVM(0) -> C2 half2
//   -> D gbuf reduce + sync -> E elementwise, h-store, out, xg, WAITVM(2),
//   sync, flag.
// Flag-protocol invariants unchanged from R8/R10/R11 (proven).
// ---------------------------------------------------------------------------
__global__ __launch_bounds__(256, 1) void lstm_kernel(
    const bf16* __restrict__ xgp, const bf16* __restrict__ wfrag,
    bf16* __restrict__ hbuf, u32* __restrict__ flags, float* __restrict__ out)
{
    __shared__ char  hstage[8 * 2064];  // h[8 rows][1024 k] bf16, pitch 2064
    __shared__ float gbuf[4][8][136];   // [wave][batch row][gate col]

    const int tid  = threadIdx.x;
    const int lane = tid & 63;
    const int wv   = tid >> 6;
    const int wg   = blockIdx.x;
    const int hg   = wg & 31;
    const int bg   = wg >> 5;

    // W fragments -> 256 regs/lane (64 x bf16x8), coalesced 16B loads
    bf16x8 wreg[64];
    {
        const bf16* wb = wfrag + ((size_t)(hg * 4 + wv) * 4096 + lane) * 8;
        #pragma unroll
        for (int f = 0; f < 64; ++f)
            wreg[f] = *(const bf16x8*)(wb + (size_t)f * 512);
    }

    const int frow  = lane & 15;
    const int b_el  = tid >> 5;                       // 0..7
    const int j_el  = tid & 31;                       // 0..31
    const int hid   = hg * 32 + j_el;

    // staging: chunk c = k-quarter c*64..+64 x rows 0..7.
    // lane -> row r = lane>>3, k8 = lane&7. 8-lane groups: 128B contiguous.
    const int goff = (lane >> 3) * 2048 + wv * 512 + (lane & 7) * 16;  // global
    const int woff = (lane >> 3) * 2064 + wv * 512 + (lane & 7) * 16;  // LDS
    // read: frag (kk,q): byte = rbase*2064 + wv*512 + q*16 + kk*64
    const int rbase = frow & 7;
    const int cbase = rbase * 2064 + wv * 512 + (lane >> 4) * 16;

    const u32* pollpA = flags + ((bg * 32 + wv * 8 + (lane & 3)) << 4);
    const u32* pollpB = flags + ((bg * 32 + wv * 8 + 4 + (lane & 3)) << 4);
    u32* myflag       = flags + ((bg * 32 + hg) << 4);

    float c = 0.f;
    u32x2 xr = load8_cached(xgp + (size_t)(bg * 8 + b_el) * NG + hid * 4);

    #pragma unroll 1
    for (int step = 0; step < T_STEPS; ++step) {
        // A1: poll this wave's first 4 producers (K-half1 ready).
        // The atomic load's implicit vmcnt(0) also drains prev-step out/xg
        // acks during the spin (idle time).
        while (__hip_atomic_load(pollpA, __ATOMIC_RELAXED,
                                 __HIP_MEMORY_SCOPE_AGENT) < (u32)step)
            __builtin_amdgcn_s_sleep(1);

        // B1: issue chunks 0,1 (half1)
        const char* hbp = (const char*)(hbuf + (step & 1) * (BATCH * HID)
                                             + (size_t)(bg * 8) * HID);
        u32x4 s0 = load16_cc(hbp + goff);
        u32x4 s1 = load16_cc(hbp + goff + 128);

        // A2: poll last 4 producers; its vmcnt(0) drains s0,s1 during the wait
        while (__hip_atomic_load(pollpB, __ATOMIC_RELAXED,
                                 __HIP_MEMORY_SCOPE_AGENT) < (u32)step)
            __builtin_amdgcn_s_sleep(1);

        // B2: issue chunks 2,3
        u32x4 s2 = load16_cc(hbp + goff + 256);
        u32x4 s3 = load16_cc(hbp + goff + 384);

        // C1: stage + compute half1 (s0,s1 already drained by poll A2)
        *(u32x4*)(hstage + woff)       = s0;
        *(u32x4*)(hstage + woff + 128) = s1;
        f32x4 acc[8] = {};
        #pragma unroll
        for (int kk = 0; kk < 4; ++kk) {
            bf16x8 a = *(const bf16x8*)(hstage + cbase + kk * 64);
            #pragma unroll
            for (int n = 0; n < 8; ++n)
                acc[n] = __builtin_amdgcn_mfma_f32_16x16x32_bf16(
                    a, wreg[kk * 8 + n], acc[n], 0, 0, 0);
        }

        // C2: chunks 2,3 landed under MFMA half1
        WAITVM(0);
        __builtin_amdgcn_sched_barrier(0);
        *(u32x4*)(hstage + woff + 256) = s2;
        *(u32x4*)(hstage + woff + 384) = s3;
        #pragma unroll
        for (int kk = 4; kk < 8; ++kk) {
            bf16x8 a = *(const bf16x8*)(hstage + cbase + kk * 64);
            #pragma unroll
            for (int n = 0; n < 8; ++n)
                acc[n] = __builtin_amdgcn_mfma_f32_16x16x32_bf16(
                    a, wreg[kk * 8 + n], acc[n], 0, 0, 0);
        }

        // D: cross-wave reduce staging (valid batch rows live in lanes 0..31)
        if (lane < 32) {
            const int q = lane >> 4;
            #pragma unroll
            for (int n = 0; n < 8; ++n)
                #pragma unroll
                for (int r = 0; r < 4; ++r)
                    gbuf[wv][q * 4 + r][n * 16 + frow] = acc[n][r];
        }
        __syncthreads();

        // E: elementwise; h-store FIRST, then out/xg (younger), WAITVM(2)
        // acks exactly the h-store -> flag publishes without HBM-ack wait.
        bf16x4 xv = __builtin_bit_cast(bf16x4, xr);
        float P[4];
        #pragma unroll
        for (int g = 0; g < 4; ++g)
            P[g] = gbuf[0][b_el][j_el * 4 + g] + gbuf[1][b_el][j_el * 4 + g]
                 + gbuf[2][b_el][j_el * 4 + g] + gbuf[3][b_el][j_el * 4 + g]
                 + (float)xv[g];
        const float ig = fsigmoid(P[0]);
        const float fg = fsigmoid(P[1]);
        const float gg = ftanh_(P[2]);
        const float og = fsigmoid(P[3]);
        c = fg * c + ig * gg;
        const float hv = og * ftanh_(c);

        const bf16 h16 = (bf16)hv;
        store2_cc(hbuf + ((step & 1) ^ 1) * (BATCH * HID)
                       + (size_t)(bg * 8 + b_el) * HID + hid,
                  (u32)__builtin_bit_cast(unsigned short, h16));       // o1
        store4_f32(out + (size_t)(step * BATCH + bg * 8 + b_el) * HID + hid, hv); // o2
        const int nx = (step + 1 < T_STEPS) ? step + 1 : step;
        xr = load8_cached(xgp + ((size_t)(nx * BATCH) + bg * 8 + b_el) * NG
                              + hid * 4);                               // o3
        WAITVM(2);                        // h-store (oldest) acked at LLC
        __builtin_amdgcn_sched_barrier(0);
        __syncthreads();                  // all waves of this WG acked
        if (tid == 0)
            __hip_atomic_store(myflag, (u32)(step + 1),
                               __ATOMIC_RELAXED, __HIP_MEMORY_SCOPE_AGENT);
    }
}

// ---------------------------------------------------------------------------
extern "C" void kernel_launch(void* const* d_in, const int* in_sizes, int n_in,
                              void* d_out, int out_size, void* d_ws, size_t ws_size,
                              hipStream_t stream) {
    const float* x   = (const float*)d_in[0];   // [512,64,1024]
    const float* wih = (const float*)d_in[1];   // [4096,1024]
    const float* whh = (const float*)d_in[2];   // [4096,1024]
    const float* bih = (const float*)d_in[3];   // [4096]
    const float* bhh = (const float*)d_in[4];   // [4096]
    float* out = (float*)d_out;                 // [512,64,1024]

    char* ws = (char*)d_ws;
    size_t off = 0;
    bf16* xgp   = (bf16*)(ws + off); off += (size_t)MROWS * NG * 2;      // 256 MB
    bf16* xb    = (bf16*)(ws + off); off += (size_t)MROWS * DIM * 2;     //  64 MB
    bf16* wihp  = (bf16*)(ws + off); off += (size_t)NG * DIM * 2;        //   8 MB
    bf16* wfrag = (bf16*)(ws + off); off += (size_t)NG * HID * 2;        //   8 MB
    float* bsum = (float*)(ws + off); off += (size_t)NG * 4;             //  16 KB
    bf16* hbuf  = (bf16*)(ws + off); off += (size_t)2 * BATCH * HID * 2; // 256 KB
    u32* flags  = (u32*)(ws + off); off += 256 * 16 * 4;                 //  16 KB
    (void)ws_size; (void)in_sizes; (void)n_in; (void)out_size;

    prep_kernel<<<2048, 256, 0, stream>>>(x, wih, whh, bih, bhh,
                                          xb, wihp, wfrag, bsum, hbuf, flags);
    gemm_kernel<<<8192, 256, 0, stream>>>(xb, wihp, bsum, xgp);
    lstm_kernel<<<256, 256, 0, stream>>>(xgp, wfrag, hbuf, flags, out);
}